// Round 12
// baseline (3394.305 us; speedup 1.0000x reference)
//
#include <hip/hip_runtime.h>

typedef _Float16 half8 __attribute__((ext_vector_type(8)));
typedef _Float16 half4v __attribute__((ext_vector_type(4)));
typedef float float4v __attribute__((ext_vector_type(4)));

#define HID 2048
#define EMBD 2048
#define BATCH 128
#define TSTEPS 256
#define STEP ((size_t)BATCH * HID)

// ---------------- small prep kernels ----------------
__global__ __launch_bounds__(256) void cast_f16_kernel(const float* __restrict__ src,
                                                       _Float16* __restrict__ dst, int n) {
    int i = (blockIdx.x * 256 + threadIdx.x) * 4;
    int stride = gridDim.x * 256 * 4;
    for (; i < n; i += stride) {
        float4v v = *(const float4v*)(src + i);
        half4v h;
        h[0] = (_Float16)v[0]; h[1] = (_Float16)v[1];
        h[2] = (_Float16)v[2]; h[3] = (_Float16)v[3];
        *(half4v*)(dst + i) = h;
    }
}

__global__ __launch_bounds__(256) void bias_kernel(const float* __restrict__ a,
                                                   const float* __restrict__ b,
                                                   float* __restrict__ dst) {
    int i = blockIdx.x * 256 + threadIdx.x;
    if (i < HID) dst[i] = a[i] + b[i];
}

// ---------------- Phase A: slots 1..256 of xb = gather(emb,x) @ W_ih^T + bias ----------
// (R9 version — manual staging; global_load_lds variant measured slower in R11)
__global__ __launch_bounds__(256) void phaseA_kernel(const int* __restrict__ x,
                                                     const float* __restrict__ emb,
                                                     const _Float16* __restrict__ w16,
                                                     const float* __restrict__ bias,
                                                     _Float16* __restrict__ xproj) {
    __shared__ __align__(16) _Float16 As[128 * 64];
    __shared__ __align__(16) _Float16 Bs[128 * 64];

    const int tid = threadIdx.x;
    const int bx  = blockIdx.x;
    const int nt = bx & 15, mt = bx >> 4;
    const long m0 = (long)mt * 128;
    const long n0 = (long)nt * 128;
    const int lane = tid & 63, w = tid >> 6;
    const int ln15 = lane & 15, kg = lane >> 4;
    const int wr = (w >> 1) * 64, wc = (w & 1) * 64;

    int xr[4];
#pragma unroll
    for (int it = 0; it < 4; ++it) xr[it] = x[m0 + ((it * 256 + tid) >> 3)];

    float4v acc[4][4];
#pragma unroll
    for (int m = 0; m < 4; ++m)
#pragma unroll
        for (int n = 0; n < 4; ++n) acc[m][n] = (float4v){0.f, 0.f, 0.f, 0.f};

    for (int kt = 0; kt < 32; ++kt) {
        __syncthreads();
#pragma unroll
        for (int it = 0; it < 4; ++it) {
            int c = it * 256 + tid;
            const float* src = emb + (long)xr[it] * EMBD + kt * 64 + (c & 7) * 8;
            float4v v0 = *(const float4v*)src;
            float4v v1 = *(const float4v*)(src + 4);
            half8 hv;
#pragma unroll
            for (int q = 0; q < 4; ++q) { hv[q] = (_Float16)v0[q]; hv[4 + q] = (_Float16)v1[q]; }
            *(half8*)(&As[c * 8]) = hv;
        }
#pragma unroll
        for (int it = 0; it < 4; ++it) {
            int c = it * 256 + tid;
            const _Float16* src = w16 + (n0 + (c >> 3)) * (long)EMBD + kt * 64 + (c & 7) * 8;
            *(half8*)(&Bs[c * 8]) = *(const half8*)src;
        }
        __syncthreads();
#pragma unroll
        for (int kk = 0; kk < 2; ++kk) {
            half8 a[4], b[4];
#pragma unroll
            for (int m = 0; m < 4; ++m)
                a[m] = *(half8*)(&As[(wr + m * 16 + ln15) * 64 + kk * 32 + kg * 8]);
#pragma unroll
            for (int n = 0; n < 4; ++n)
                b[n] = *(half8*)(&Bs[(wc + n * 16 + ln15) * 64 + kk * 32 + kg * 8]);
            // swapped operands -> transposed fragment: lane holds 4 consecutive cols
#pragma unroll
            for (int m = 0; m < 4; ++m)
#pragma unroll
                for (int n = 0; n < 4; ++n)
                    acc[m][n] = __builtin_amdgcn_mfma_f32_16x16x32_f16(b[n], a[m], acc[m][n], 0, 0, 0);
        }
    }
#pragma unroll
    for (int m = 0; m < 4; ++m) {
        long mg = m0 + wr + m * 16 + ln15;
#pragma unroll
        for (int n = 0; n < 4; ++n) {
            int nb = (int)n0 + wc + n * 16 + kg * 4;
            float4v bv = *(const float4v*)(bias + nb);
            union { half4v h; unsigned long long u; } pk;
#pragma unroll
            for (int r = 0; r < 4; ++r) pk.h[r] = (_Float16)(acc[m][n][r] + bv[r]);
            *(unsigned long long*)(xproj + mg * HID + nb) = pk.u;
        }
    }
}

// ---------------- Phase B: persistent scan — single-wave paced poll + LDS relay ------
// R9 compute structure (proven). 256 blocks x 256 thr. gid=bx&3 rows, sub=bx>>2 cols.
// Wave (pr=w>>1, kh=w&1): 16 rows x 32 cols x k-half; part-reduce in LDS (stride 33).
// Slot-chain: bias[s] in xb slot s+1 (sc1 reads); h_{s+1} -> slot s (sc1 store);
// post-gate h reads plain cacheable (L2-shared per XCD).
// NEW: per-WAVE byte flags (4/block, 4 lines/group). Producer tail = own vmcnt drain
// + own flag byte (no block barrier). Gate: ONLY wave 0 polls (64 wave-requests per
// group instead of 256 -> no L3-bank backlog), s_sleep-paced retry, SWAR byte test;
// waves 1-3 spin on LDS goflag relay. WAR guard for part[] is the gate itself:
// a wave rewrites part only after ALL group waves posted s (=> all reduce-reads done).
__global__ __launch_bounds__(256, 1) void scan_kernel(_Float16* __restrict__ xb,
                                                      const _Float16* __restrict__ whh,
                                                      float* __restrict__ hlast,
                                                      unsigned char* __restrict__ flags) {
    __shared__ __align__(16) _Float16 Wl[32 * 2048];  // 128 KB
    __shared__ float part[4][16 * 33];
    __shared__ unsigned goflag;

    const int tid = threadIdx.x;
    const int bx = blockIdx.x;
    const int gid = bx & 3, sub = bx >> 2;
    const int m0 = gid * 32, n0 = sub * 32;
    const int lane = tid & 63, w = tid >> 6;
    const int ln15 = lane & 15, kg = lane >> 4;
    const int pr = w >> 1, kh = w & 1;

    // stage W[n0..n0+32) x [0..2048): byte = col*4096 + ((k*2) ^ ((col&7)<<4))
    for (int it = 0; it < 32; ++it) {
        int c = it * 256 + tid;
        int col = c >> 8, ch = c & 255;
        half8 v = *(const half8*)(whh + (long)(n0 + col) * HID + ch * 8);
        *(half8*)((char*)Wl + col * 4096 + ((ch * 16) ^ ((col & 7) << 4))) = v;
    }
    if (tid == 0) goflag = 0;
    __syncthreads();

    unsigned char* gfl = flags + gid * 256;                 // 256 wave-flags, 4 lines
    const unsigned long long* gfl64 = (const unsigned long long*)gfl;
    const size_t arow = (size_t)(m0 + pr * 16 + ln15);      // h row this lane loads
    const int wb0 = ln15 * 4096, wb1 = (16 + ln15) * 4096;  // W LDS row bases
    const int swz = (ln15 & 7) << 4;
    const int kb = kh * 2048;                               // k-half byte offset
    const int rp = tid >> 7, ridx = tid & 127;              // reduce/output mapping
    const int rrow = ridx >> 3, rc4 = (ridx & 7) * 4;
    const size_t oidx = (size_t)(m0 + rp * 16 + rrow) * HID + n0 + rc4;
    const int myflag = sub * 4 + w;                         // this wave's flag byte

    for (int s = 0; s < TSTEPS; ++s) {
        // bias[s] from slot s+1 — sc1 bypass (keeps slot out of all caches)
        unsigned long long xbits = __hip_atomic_load(
            (const unsigned long long*)(xb + (size_t)(s + 1) * STEP + oidx),
            __ATOMIC_RELAXED, __HIP_MEMORY_SCOPE_AGENT);

        float4v acc0 = (float4v){0.f, 0.f, 0.f, 0.f};
        float4v acc1 = (float4v){0.f, 0.f, 0.f, 0.f};
        if (s > 0) {
            if (w == 0) {
                // gate: no flag byte equals (s-1)  [values in {s-1,s,s+1}, no wrap]
                unsigned long long pat =
                    (unsigned long long)(unsigned char)(s - 1) * 0x0101010101010101ull;
                for (;;) {
                    bool ok = true;
                    if (lane < 32) {
                        unsigned long long v = __hip_atomic_load(gfl64 + lane,
                                                __ATOMIC_RELAXED, __HIP_MEMORY_SCOPE_AGENT);
                        unsigned long long xx = v ^ pat;
                        ok = !((xx - 0x0101010101010101ull) & ~xx & 0x8080808080808080ull);
                    }
                    if (__all(ok)) break;
                    __builtin_amdgcn_s_sleep(1);
                }
                __hip_atomic_store(&goflag, (unsigned)s, __ATOMIC_RELAXED,
                                   __HIP_MEMORY_SCOPE_WORKGROUP);
            } else {
                while (__hip_atomic_load(&goflag, __ATOMIC_RELAXED,
                                         __HIP_MEMORY_SCOPE_WORKGROUP) < (unsigned)s) {}
            }
            asm volatile("" ::: "memory");        // no hoisting h loads above gate
            __builtin_amdgcn_sched_barrier(0);

            // ---- h_s from slot s-1: plain cacheable loads (L2-shared per XCD)
            const _Float16* hrow = xb + (size_t)(s - 1) * STEP + arow * HID + kh * 1024;
#pragma unroll
            for (int j = 0; j < 32; ++j) {
                half8 a = *(const half8*)(hrow + j * 32 + kg * 8);
                int k2 = kb + j * 64 + kg * 16;
                half8 b0 = *(half8*)((char*)Wl + wb0 + (k2 ^ swz));
                half8 b1 = *(half8*)((char*)Wl + wb1 + (k2 ^ swz));
                acc0 = __builtin_amdgcn_mfma_f32_16x16x32_f16(a, b0, acc0, 0, 0, 0);
                acc1 = __builtin_amdgcn_mfma_f32_16x16x32_f16(a, b1, acc1, 0, 0, 0);
            }
            // partials to LDS (stride 33)
#pragma unroll
            for (int r = 0; r < 4; ++r) {
                part[w][(kg * 4 + r) * 33 + ln15] = acc0[r];
                part[w][(kg * 4 + r) * 33 + 16 + ln15] = acc1[r];
            }
        }

        float s0 = 0.f, s1 = 0.f, s2 = 0.f, s3 = 0.f;
        if (s > 0) {
            __syncthreads();   // part visible to reducers (only barrier per step)
            const float* p0 = &part[2 * rp][rrow * 33 + rc4];
            const float* p1 = &part[2 * rp + 1][rrow * 33 + rc4];
            s0 = p0[0] + p1[0]; s1 = p0[1] + p1[1];
            s2 = p0[2] + p1[2]; s3 = p0[3] + p1[3];
        }
        union { unsigned long long u; half4v h; } xbv; xbv.u = xbits;
        float o0 = tanhf(s0 + (float)xbv.h[0]);
        float o1 = tanhf(s1 + (float)xbv.h[1]);
        float o2 = tanhf(s2 + (float)xbv.h[2]);
        float o3 = tanhf(s3 + (float)xbv.h[3]);

        if (s < TSTEPS - 1) {
            // h_{s+1} -> slot s (sc1); wave drains OWN stores, posts OWN flag byte
            union { half4v h; unsigned long long u; } pk;
            pk.h[0] = (_Float16)o0; pk.h[1] = (_Float16)o1;
            pk.h[2] = (_Float16)o2; pk.h[3] = (_Float16)o3;
            __hip_atomic_store((unsigned long long*)(xb + (size_t)s * STEP + oidx),
                               pk.u, __ATOMIC_RELAXED, __HIP_MEMORY_SCOPE_AGENT);
            asm volatile("s_waitcnt vmcnt(0)" ::: "memory");  // own h-stores at L3
            if (lane == 0)
                __hip_atomic_store(&gfl[myflag], (unsigned char)(s + 1),
                                   __ATOMIC_RELAXED, __HIP_MEMORY_SCOPE_AGENT);
        } else {
            float4v f = {o0, o1, o2, o3};
            *(float4v*)(hlast + oidx) = f;
        }
    }
}

// ---------------- head ----------------
// fc1 tiled: 16 blocks x 8 batch rows; fc1w read ONCE per block (32MB total)
__global__ __launch_bounds__(256) void fc1_kernel(const float* __restrict__ hlast,
                                                  const float* __restrict__ w,
                                                  const float* __restrict__ b,
                                                  float* __restrict__ z) {
    __shared__ float hs[8][256];
    const int blk = blockIdx.x;     // 16
    const int j = threadIdx.x;      // 0..255 output col
    const int bb0 = blk * 8;
    float acc[8];
#pragma unroll
    for (int r = 0; r < 8; ++r) acc[r] = 0.f;
    const float* wr = w + (long)j * HID;
    const int sr = j >> 5, sc = (j & 31) * 8;

    for (int kt = 0; kt < 8; ++kt) {
        __syncthreads();
        float4v h0 = *(const float4v*)(hlast + (long)(bb0 + sr) * HID + kt * 256 + sc);
        float4v h1 = *(const float4v*)(hlast + (long)(bb0 + sr) * HID + kt * 256 + sc + 4);
        *(float4v*)&hs[sr][sc] = h0;
        *(float4v*)&hs[sr][sc + 4] = h1;
        __syncthreads();
        for (int k = 0; k < 256; k += 4) {
            float4v wv = *(const float4v*)(wr + kt * 256 + k);
#pragma unroll
            for (int r = 0; r < 8; ++r) {
                float4v hv = *(const float4v*)&hs[r][k];
                acc[r] += hv[0] * wv[0] + hv[1] * wv[1] + hv[2] * wv[2] + hv[3] * wv[3];
            }
        }
    }
    float bj = b[j];
#pragma unroll
    for (int r = 0; r < 8; ++r) z[(bb0 + r) * 256 + j] = fmaxf(acc[r] + bj, 0.f);
}

__global__ __launch_bounds__(256) void fc2_kernel(const float* __restrict__ z,
                                                  const float* __restrict__ w,
                                                  const float* __restrict__ b,
                                                  float* __restrict__ out) {
    __shared__ float red[4];
    int bb = blockIdx.x;
    int tid = threadIdx.x;
    float zv = z[bb * 256 + tid];
    for (int c = 0; c < 3; ++c) {
        float s = zv * w[c * 256 + tid];
        for (int off = 32; off > 0; off >>= 1) s += __shfl_down(s, off, 64);
        if ((tid & 63) == 0) red[tid >> 6] = s;
        __syncthreads();
        if (tid == 0) out[bb * 3 + c] = red[0] + red[1] + red[2] + red[3] + b[c];
        __syncthreads();
    }
}

// ---------------- launch ----------------
extern "C" void kernel_launch(void* const* d_in, const int* in_sizes, int n_in,
                              void* d_out, int out_size, void* d_ws, size_t ws_size,
                              hipStream_t stream) {
    const int*   x    = (const int*)d_in[0];
    const float* emb  = (const float*)d_in[1];
    const float* Wih  = (const float*)d_in[2];
    const float* Whh  = (const float*)d_in[3];
    const float* bih  = (const float*)d_in[4];
    const float* bhh  = (const float*)d_in[5];
    const float* fc1w = (const float*)d_in[6];
    const float* fc1b = (const float*)d_in[7];
    const float* fc2w = (const float*)d_in[8];
    const float* fc2b = (const float*)d_in[9];
    float* out = (float*)d_out;

    char* ws = (char*)d_ws;
    size_t off = 0;
    _Float16* xb    = (_Float16*)(ws + off); off += 257 * STEP * 2;         // 134.7 MB
    _Float16* wih16 = (_Float16*)(ws + off); off += (size_t)HID * EMBD * 2; // 8 MB
    _Float16* whh16 = (_Float16*)(ws + off); off += (size_t)HID * HID * 2;  // 8 MB
    float*    bias  = (float*)(ws + off);    off += (size_t)HID * 4;
    float*    hlast = (float*)(ws + off);    off += (size_t)BATCH * HID * 4;
    float*    z     = (float*)(ws + off);    off += (size_t)BATCH * 256 * 4;
    unsigned char* flags = (unsigned char*)(ws + off); off += 1024;  // 4 groups x 256B

    hipMemsetAsync(flags, 0, 1024, stream);

    cast_f16_kernel<<<4096, 256, 0, stream>>>(Wih, wih16, HID * EMBD);
    cast_f16_kernel<<<4096, 256, 0, stream>>>(Whh, whh16, HID * HID);
    bias_kernel<<<8, 256, 0, stream>>>(bih, bhh, bias);

    // phaseA writes bias[s] into slot s+1
    phaseA_kernel<<<4096, 256, 0, stream>>>(x, emb, wih16, bias, xb + STEP);

    void* args[] = {(void*)&xb, (void*)&whh16, (void*)&hlast, (void*)&flags};
    hipLaunchCooperativeKernel((const void*)scan_kernel, dim3(256), dim3(256), args, 0, stream);

    fc1_kernel<<<16, 256, 0, stream>>>(hlast, fc1w, fc1b, z);
    fc2_kernel<<<BATCH, 256, 0, stream>>>(z, fc2w, fc2b, out);
}

// Round 13
// 3171.449 us; speedup vs baseline: 1.0703x; 1.0703x over previous
//
#include <hip/hip_runtime.h>

typedef _Float16 half8 __attribute__((ext_vector_type(8)));
typedef _Float16 half4v __attribute__((ext_vector_type(4)));
typedef float float4v __attribute__((ext_vector_type(4)));

#define HID 2048
#define EMBD 2048
#define BATCH 128
#define TSTEPS 256
#define STEP ((size_t)BATCH * HID)

// ---------------- small prep kernels ----------------
__global__ __launch_bounds__(256) void cast_f16_kernel(const float* __restrict__ src,
                                                       _Float16* __restrict__ dst, int n) {
    int i = (blockIdx.x * 256 + threadIdx.x) * 4;
    int stride = gridDim.x * 256 * 4;
    for (; i < n; i += stride) {
        float4v v = *(const float4v*)(src + i);
        half4v h;
        h[0] = (_Float16)v[0]; h[1] = (_Float16)v[1];
        h[2] = (_Float16)v[2]; h[3] = (_Float16)v[3];
        *(half4v*)(dst + i) = h;
    }
}

__global__ __launch_bounds__(256) void bias_kernel(const float* __restrict__ a,
                                                   const float* __restrict__ b,
                                                   float* __restrict__ dst) {
    int i = blockIdx.x * 256 + threadIdx.x;
    if (i < HID) dst[i] = a[i] + b[i];
}

// ---------------- Phase A: slots 1..256 of xb = gather(emb,x) @ W_ih^T + bias ----------
__global__ __launch_bounds__(256) void phaseA_kernel(const int* __restrict__ x,
                                                     const float* __restrict__ emb,
                                                     const _Float16* __restrict__ w16,
                                                     const float* __restrict__ bias,
                                                     _Float16* __restrict__ xproj) {
    __shared__ __align__(16) _Float16 As[128 * 64];
    __shared__ __align__(16) _Float16 Bs[128 * 64];

    const int tid = threadIdx.x;
    const int bx  = blockIdx.x;
    const int nt = bx & 15, mt = bx >> 4;
    const long m0 = (long)mt * 128;
    const long n0 = (long)nt * 128;
    const int lane = tid & 63, w = tid >> 6;
    const int ln15 = lane & 15, kg = lane >> 4;
    const int wr = (w >> 1) * 64, wc = (w & 1) * 64;

    int xr[4];
#pragma unroll
    for (int it = 0; it < 4; ++it) xr[it] = x[m0 + ((it * 256 + tid) >> 3)];

    float4v acc[4][4];
#pragma unroll
    for (int m = 0; m < 4; ++m)
#pragma unroll
        for (int n = 0; n < 4; ++n) acc[m][n] = (float4v){0.f, 0.f, 0.f, 0.f};

    for (int kt = 0; kt < 32; ++kt) {
        __syncthreads();
#pragma unroll
        for (int it = 0; it < 4; ++it) {
            int c = it * 256 + tid;
            const float* src = emb + (long)xr[it] * EMBD + kt * 64 + (c & 7) * 8;
            float4v v0 = *(const float4v*)src;
            float4v v1 = *(const float4v*)(src + 4);
            half8 hv;
#pragma unroll
            for (int q = 0; q < 4; ++q) { hv[q] = (_Float16)v0[q]; hv[4 + q] = (_Float16)v1[q]; }
            *(half8*)(&As[c * 8]) = hv;
        }
#pragma unroll
        for (int it = 0; it < 4; ++it) {
            int c = it * 256 + tid;
            const _Float16* src = w16 + (n0 + (c >> 3)) * (long)EMBD + kt * 64 + (c & 7) * 8;
            *(half8*)(&Bs[c * 8]) = *(const half8*)src;
        }
        __syncthreads();
#pragma unroll
        for (int kk = 0; kk < 2; ++kk) {
            half8 a[4], b[4];
#pragma unroll
            for (int m = 0; m < 4; ++m)
                a[m] = *(half8*)(&As[(wr + m * 16 + ln15) * 64 + kk * 32 + kg * 8]);
#pragma unroll
            for (int n = 0; n < 4; ++n)
                b[n] = *(half8*)(&Bs[(wc + n * 16 + ln15) * 64 + kk * 32 + kg * 8]);
            // swapped operands -> transposed fragment: lane holds 4 consecutive cols
#pragma unroll
            for (int m = 0; m < 4; ++m)
#pragma unroll
                for (int n = 0; n < 4; ++n)
                    acc[m][n] = __builtin_amdgcn_mfma_f32_16x16x32_f16(b[n], a[m], acc[m][n], 0, 0, 0);
        }
    }
#pragma unroll
    for (int m = 0; m < 4; ++m) {
        long mg = m0 + wr + m * 16 + ln15;
#pragma unroll
        for (int n = 0; n < 4; ++n) {
            int nb = (int)n0 + wc + n * 16 + kg * 4;
            float4v bv = *(const float4v*)(bias + nb);
            union { half4v h; unsigned long long u; } pk;
#pragma unroll
            for (int r = 0; r < 4; ++r) pk.h[r] = (_Float16)(acc[m][n][r] + bv[r]);
            *(unsigned long long*)(xproj + mg * HID + nb) = pk.u;
        }
    }
}

// ---------------- Phase B: XCD-partitioned persistent scan ----------------
// 256 blocks x 256 thr, 1/CU. Blocks self-assign: xcd = HW_REG_XCC_ID, slot =
// atomicAdd(per-XCD ctr) in 0..31 (pigeonhole: capacity 1/CU => exactly 32/XCD).
// Group g = XCD pair (2g, 2g+1) owns batch rows [32g,+32). XCD parity kh = K-half.
// Block (xcd, slot=c): W cols [64c,+64) x K [1024kh,+1024) in LDS (128 KB).
// Finishers K-ALIGNED: even XCD finishes cols [0,1024) (c<16), odd cols [1024,2048)
// (c>=16)  =>  every block's h input (its K-range) is produced ON ITS OWN XCD:
// h stores/loads are PLAIN (L2-local, coherent via shared per-XCD L2; consumer L1/L2
// never held those fresh slot-chained addresses). Happens-before: h plain stores ->
// __syncthreads (vmcnt drain = L2 ack) -> sc1 hflag; consumers poll 16 sc1 flags.
// Cross-XCD traffic = ONLY the 8 KB f32 partial + pflag per pair per step (sc1).
// Slot-chain: bias[s] in xb slot s+1 (sc1 reads); h_{s+1} -> slot s.
__global__ __launch_bounds__(256, 1) void scan_kernel(_Float16* __restrict__ xb,
                                                      const _Float16* __restrict__ whh,
                                                      float* __restrict__ hlast,
                                                      unsigned* __restrict__ ctrs,
                                                      unsigned* __restrict__ pfl,
                                                      unsigned* __restrict__ hfl,
                                                      float* __restrict__ pexch) {
    __shared__ __align__(16) _Float16 Wl[64 * 1024];   // 128 KB
    __shared__ __align__(16) float part[2][16 * 68];   // 8.5 KB
    __shared__ int sh_ids[2];

    const int tid = threadIdx.x;
    if (tid == 0) {
        unsigned xcc;
        asm volatile("s_getreg_b32 %0, hwreg(HW_REG_XCC_ID)" : "=s"(xcc));
        unsigned slot = atomicAdd(&ctrs[xcc * 32], 1u);
        sh_ids[0] = (int)xcc;
        sh_ids[1] = (int)slot;
    }
    __syncthreads();
    const int xcd = sh_ids[0], slot = sh_ids[1];
    const int g = xcd >> 1, kh = xcd & 1, c = slot;
    const int m0 = g * 32;
    const long n0 = (long)c * 64;
    const int kbase = kh * 1024;
    const bool fin = (kh == 0) ? (c < 16) : (c >= 16);
    const int pairid = g * 32 + c;
    const int fi = (kh == 0) ? c : (c - 16);

    // stage W[n0..n0+64) x [kbase..+1024): 2048B/col row, XOR-swizzled k within row
    for (int it = 0; it < 32; ++it) {
        int idx = it * 256 + tid;                 // 8192 chunks of 8 halves
        int col = idx >> 7, ch = idx & 127;
        half8 v = *(const half8*)(whh + (n0 + col) * (long)HID + kbase + ch * 8);
        *(half8*)((char*)Wl + col * 2048 + ((ch * 16) ^ ((col & 7) << 4))) = v;
    }
    __syncthreads();

    const int lane = tid & 63, w = tid >> 6;
    const int ln15 = lane & 15, kg = lane >> 4;
    const int mi = w >> 1, kj = w & 1;            // wave = (row-half, k-quarter-half)
    const int swz = (ln15 & 7) << 4;
    const size_t arow = (size_t)(m0 + mi * 16 + ln15);
    // packer/exchange mapping: thread -> (row 0..31, col-octet)
    const int prow = tid >> 3;
    const int pc8 = (tid & 7) * 8;
    const int pmi = prow >> 4;
    const int ppo = (prow & 15) * 68 + pc8;
    const size_t gidx = (size_t)(m0 + prow) * HID + n0 + pc8;
    unsigned long long* pex64 = (unsigned long long*)pexch + (size_t)pairid * 1024
                                + (size_t)(prow * 64 + pc8) / 2;
    const unsigned long long* hfl64 = (const unsigned long long*)(hfl + xcd * 64);

    for (int s = 0; s < TSTEPS; ++s) {
        // bias prefetch (finishers only; sc1 keeps slot out of caches)
        unsigned long long b0 = 0, b1 = 0;
        if (fin) {
            const unsigned long long* bp =
                (const unsigned long long*)(xb + (size_t)(s + 1) * STEP + gidx);
            b0 = __hip_atomic_load(bp, __ATOMIC_RELAXED, __HIP_MEMORY_SCOPE_AGENT);
            b1 = __hip_atomic_load(bp + 1, __ATOMIC_RELAXED, __HIP_MEMORY_SCOPE_AGENT);
        }

        if (s > 0) {
            // ---- gate: own XCD's 16 finisher flags >= s (sc1 poll, paced)
            for (;;) {
                bool ok = true;
                if (lane < 8) {
                    unsigned long long v = __hip_atomic_load(hfl64 + lane,
                                            __ATOMIC_RELAXED, __HIP_MEMORY_SCOPE_AGENT);
                    ok = ((unsigned)v >= (unsigned)s) && ((unsigned)(v >> 32) >= (unsigned)s);
                }
                if (__all(ok)) break;
                __builtin_amdgcn_s_sleep(1);
            }
            asm volatile("" ::: "memory");
            __builtin_amdgcn_sched_barrier(0);

            // ---- MFMA: 16 rows (mi) x 64 cols x 512 K (kj) ; h = PLAIN loads (own L2)
            const _Float16* hrow = xb + (size_t)(s - 1) * STEP + arow * HID + kbase + kj * 512;
            float4v acc[4];
#pragma unroll
            for (int nf = 0; nf < 4; ++nf) acc[nf] = (float4v){0.f, 0.f, 0.f, 0.f};
#pragma unroll
            for (int j = 0; j < 16; ++j) {
                half8 a = *(const half8*)(hrow + j * 32 + kg * 8);
                int k2 = (kj * 512 + j * 32 + kg * 8) * 2;
#pragma unroll
                for (int nf = 0; nf < 4; ++nf) {
                    half8 b = *(half8*)((char*)Wl + (nf * 16 + ln15) * 2048 + (k2 ^ swz));
                    acc[nf] = __builtin_amdgcn_mfma_f32_16x16x32_f16(a, b, acc[nf], 0, 0, 0);
                }
            }
            if (kj == 1) {
#pragma unroll
                for (int nf = 0; nf < 4; ++nf)
#pragma unroll
                    for (int r = 0; r < 4; ++r)
                        part[mi][(kg * 4 + r) * 68 + nf * 16 + ln15] = acc[nf][r];
            }
            __syncthreads();   // B1: kj=1 partials visible
            if (kj == 0) {
#pragma unroll
                for (int nf = 0; nf < 4; ++nf)
#pragma unroll
                    for (int r = 0; r < 4; ++r)
                        part[mi][(kg * 4 + r) * 68 + nf * 16 + ln15] += acc[nf][r];
            }
            __syncthreads();   // B2: block partial merged in part[]
        }

        if (!fin) {
            if (s > 0) {
                // ---- sender: ship 8 f32 per thread (coalesced) to pair buffer, sc1
                union { float4v f; unsigned long long u[2]; } ua, ub;
                ua.f = *(const float4v*)&part[pmi][ppo];
                ub.f = *(const float4v*)&part[pmi][ppo + 4];
                __hip_atomic_store(pex64 + 0, ua.u[0], __ATOMIC_RELAXED, __HIP_MEMORY_SCOPE_AGENT);
                __hip_atomic_store(pex64 + 1, ua.u[1], __ATOMIC_RELAXED, __HIP_MEMORY_SCOPE_AGENT);
                __hip_atomic_store(pex64 + 2, ub.u[0], __ATOMIC_RELAXED, __HIP_MEMORY_SCOPE_AGENT);
                __hip_atomic_store(pex64 + 3, ub.u[1], __ATOMIC_RELAXED, __HIP_MEMORY_SCOPE_AGENT);
                __syncthreads();   // drains sc1 stores (vmcnt before s_barrier)
                if (tid == 0)
                    __hip_atomic_store(&pfl[pairid], (unsigned)(s + 1),
                                       __ATOMIC_RELAXED, __HIP_MEMORY_SCOPE_AGENT);
            }
        } else {
            float o[8];
            if (s > 0) {
                // ---- finisher: wait partner partial (sc1 cross-XCD)
                while (__hip_atomic_load(&pfl[pairid], __ATOMIC_RELAXED,
                                         __HIP_MEMORY_SCOPE_AGENT) <= (unsigned)s)
                    __builtin_amdgcn_s_sleep(1);
                asm volatile("" ::: "memory");
                __builtin_amdgcn_sched_barrier(0);
                union { unsigned long long u[2]; float f[4]; } va, vb;
                va.u[0] = __hip_atomic_load(pex64 + 0, __ATOMIC_RELAXED, __HIP_MEMORY_SCOPE_AGENT);
                va.u[1] = __hip_atomic_load(pex64 + 1, __ATOMIC_RELAXED, __HIP_MEMORY_SCOPE_AGENT);
                vb.u[0] = __hip_atomic_load(pex64 + 2, __ATOMIC_RELAXED, __HIP_MEMORY_SCOPE_AGENT);
                vb.u[1] = __hip_atomic_load(pex64 + 3, __ATOMIC_RELAXED, __HIP_MEMORY_SCOPE_AGENT);
                float4v ma = *(const float4v*)&part[pmi][ppo];
                float4v mb = *(const float4v*)&part[pmi][ppo + 4];
#pragma unroll
                for (int i = 0; i < 4; ++i) { o[i] = ma[i] + va.f[i]; o[4 + i] = mb[i] + vb.f[i]; }
            } else {
#pragma unroll
                for (int i = 0; i < 8; ++i) o[i] = 0.f;
            }
            union { unsigned long long u; half4v h; } xv0, xv1;
            xv0.u = b0; xv1.u = b1;
            float t[8];
#pragma unroll
            for (int i = 0; i < 4; ++i) {
                t[i]     = tanhf(o[i]     + (float)xv0.h[i]);
                t[4 + i] = tanhf(o[4 + i] + (float)xv1.h[i]);
            }
            if (s < TSTEPS - 1) {
                half8 hv;
#pragma unroll
                for (int i = 0; i < 8; ++i) hv[i] = (_Float16)t[i];
                *(half8*)(xb + (size_t)s * STEP + gidx) = hv;   // PLAIN -> own L2
                __syncthreads();   // vmcnt drain: all h stores at L2 before flag
                if (tid == 0)
                    __hip_atomic_store(&hfl[xcd * 64 + fi], (unsigned)(s + 1),
                                       __ATOMIC_RELAXED, __HIP_MEMORY_SCOPE_AGENT);
            } else {
                float4v f0 = {t[0], t[1], t[2], t[3]};
                float4v f1 = {t[4], t[5], t[6], t[7]};
                *(float4v*)(hlast + gidx) = f0;
                *(float4v*)(hlast + gidx + 4) = f1;
            }
        }
    }
}

// ---------------- head ----------------
// fc1 tiled: 16 blocks x 8 batch rows; fc1w read ONCE per block (32MB total)
__global__ __launch_bounds__(256) void fc1_kernel(const float* __restrict__ hlast,
                                                  const float* __restrict__ w,
                                                  const float* __restrict__ b,
                                                  float* __restrict__ z) {
    __shared__ float hs[8][256];
    const int blk = blockIdx.x;
    const int j = threadIdx.x;
    const int bb0 = blk * 8;
    float acc[8];
#pragma unroll
    for (int r = 0; r < 8; ++r) acc[r] = 0.f;
    const float* wr = w + (long)j * HID;
    const int sr = j >> 5, sc = (j & 31) * 8;

    for (int kt = 0; kt < 8; ++kt) {
        __syncthreads();
        float4v h0 = *(const float4v*)(hlast + (long)(bb0 + sr) * HID + kt * 256 + sc);
        float4v h1 = *(const float4v*)(hlast + (long)(bb0 + sr) * HID + kt * 256 + sc + 4);
        *(float4v*)&hs[sr][sc] = h0;
        *(float4v*)&hs[sr][sc + 4] = h1;
        __syncthreads();
        for (int k = 0; k < 256; k += 4) {
            float4v wv = *(const float4v*)(wr + kt * 256 + k);
#pragma unroll
            for (int r = 0; r < 8; ++r) {
                float4v hv = *(const float4v*)&hs[r][k];
                acc[r] += hv[0] * wv[0] + hv[1] * wv[1] + hv[2] * wv[2] + hv[3] * wv[3];
            }
        }
    }
    float bj = b[j];
#pragma unroll
    for (int r = 0; r < 8; ++r) z[(bb0 + r) * 256 + j] = fmaxf(acc[r] + bj, 0.f);
}

__global__ __launch_bounds__(256) void fc2_kernel(const float* __restrict__ z,
                                                  const float* __restrict__ w,
                                                  const float* __restrict__ b,
                                                  float* __restrict__ out) {
    __shared__ float red[4];
    int bb = blockIdx.x;
    int tid = threadIdx.x;
    float zv = z[bb * 256 + tid];
    for (int c = 0; c < 3; ++c) {
        float s = zv * w[c * 256 + tid];
        for (int off = 32; off > 0; off >>= 1) s += __shfl_down(s, off, 64);
        if ((tid & 63) == 0) red[tid >> 6] = s;
        __syncthreads();
        if (tid == 0) out[bb * 3 + c] = red[0] + red[1] + red[2] + red[3] + b[c];
        __syncthreads();
    }
}

// ---------------- launch ----------------
extern "C" void kernel_launch(void* const* d_in, const int* in_sizes, int n_in,
                              void* d_out, int out_size, void* d_ws, size_t ws_size,
                              hipStream_t stream) {
    const int*   x    = (const int*)d_in[0];
    const float* emb  = (const float*)d_in[1];
    const float* Wih  = (const float*)d_in[2];
    const float* Whh  = (const float*)d_in[3];
    const float* bih  = (const float*)d_in[4];
    const float* bhh  = (const float*)d_in[5];
    const float* fc1w = (const float*)d_in[6];
    const float* fc1b = (const float*)d_in[7];
    const float* fc2w = (const float*)d_in[8];
    const float* fc2b = (const float*)d_in[9];
    float* out = (float*)d_out;

    char* ws = (char*)d_ws;
    size_t off = 0;
    _Float16* xb    = (_Float16*)(ws + off); off += 257 * STEP * 2;         // 134.7 MB
    _Float16* wih16 = (_Float16*)(ws + off); off += (size_t)HID * EMBD * 2; // 8 MB
    _Float16* whh16 = (_Float16*)(ws + off); off += (size_t)HID * HID * 2;  // 8 MB
    float*    bias  = (float*)(ws + off);    off += (size_t)HID * 4;
    float*    hlast = (float*)(ws + off);    off += (size_t)BATCH * HID * 4;
    float*    z     = (float*)(ws + off);    off += (size_t)BATCH * 256 * 4;
    unsigned* ctrs  = (unsigned*)(ws + off); off += 8 * 32 * 4;   // 1 KB, per-XCD claim
    unsigned* pfl   = (unsigned*)(ws + off); off += 128 * 4;      // pair flags
    unsigned* hfl   = (unsigned*)(ws + off); off += 8 * 64 * 4;   // per-XCD finisher flags
    float*    pexch = (float*)(ws + off);    off += (size_t)128 * 2048 * 4;  // 1 MB partials

    // re-zero all control state every launch (graph-replay safe)
    hipMemsetAsync(ctrs, 0, (8 * 32 + 128 + 8 * 64) * 4, stream);

    cast_f16_kernel<<<4096, 256, 0, stream>>>(Wih, wih16, HID * EMBD);
    cast_f16_kernel<<<4096, 256, 0, stream>>>(Whh, whh16, HID * HID);
    bias_kernel<<<8, 256, 0, stream>>>(bih, bhh, bias);

    // phaseA writes bias[s] into slot s+1
    phaseA_kernel<<<4096, 256, 0, stream>>>(x, emb, wih16, bias, xb + STEP);

    void* args[] = {(void*)&xb, (void*)&whh16, (void*)&hlast,
                    (void*)&ctrs, (void*)&pfl, (void*)&hfl, (void*)&pexch};
    hipLaunchCooperativeKernel((const void*)scan_kernel, dim3(256), dim3(256), args, 0, stream);

    fc1_kernel<<<16, 256, 0, stream>>>(hlast, fc1w, fc1b, z);
    fc2_kernel<<<BATCH, 256, 0, stream>>>(z, fc2w, fc2b, out);
}